// Round 7
// baseline (202.565 us; speedup 1.0000x reference)
//
#include <hip/hip_runtime.h>

#define NETS   64
#define NNODES 288
#define NHID   256
#define NOUT   32
#define KCON   32
#define NBATCH 1024
#define TILE   16                    // batches per block
#define NPAIR  144
#define ROWB   (TILE * 4)            // 64 B per LDS state row (16 batches x f32)
#define LDSZ   (386 * ROWB)          // 24,704 B -> 6 blocks/CU

#if defined(__has_builtin)
#if __has_builtin(__builtin_amdgcn_permlane16_swap)
#define HAVE_PL16 1
#endif
#if __has_builtin(__builtin_amdgcn_permlane32_swap)
#define HAVE_PL32 1
#endif
#endif

__device__ __forceinline__ float xor16_add(float a) {
#ifdef HAVE_PL16
    auto r = __builtin_amdgcn_permlane16_swap(__float_as_uint(a), __float_as_uint(a),
                                              false, false);
    return __uint_as_float(r[0]) + __uint_as_float(r[1]);
#else
    return a + __shfl_xor(a, 16, 64);
#endif
}
__device__ __forceinline__ float xor32_add(float a) {
#ifdef HAVE_PL32
    auto r = __builtin_amdgcn_permlane32_swap(__float_as_uint(a), __float_as_uint(a),
                                              false, false);
    return __uint_as_float(r[0]) + __uint_as_float(r[1]);
#else
    return a + __shfl_xor(a, 32, 64);
#endif
}

__device__ __forceinline__ unsigned f2bf(float f) {
    unsigned b = __float_as_uint(f);
    return (b + 0x7FFFu + ((b >> 16) & 1u)) >> 16;
}
__device__ __forceinline__ float bf2f(unsigned short u) {
    return __uint_as_float(((unsigned)u) << 16);
}

// ---- prep: meta re-packed per-lane-contiguous ----
// meta[net][pair t][s][kq][j 0..7] = { lds_byte_off = idx*ROWB, w_f32_bits }
__global__ __launch_bounds__(256) void prep_meta(const float* __restrict__ W,
                                                 const int* __restrict__ conn,
                                                 int2* __restrict__ meta) {
    int g = blockIdx.x * 256 + threadIdx.x;      // 64*288*32 = 589,824 exact
    int net = g / 9216;
    int rem = g - net * 9216;
    int node = rem >> 5, k = rem & 31;
    int idx = conn[g];                           // 0..385
    float w = W[(size_t)idx * NNODES + node];
    int didx = net * 9216 + (node >> 1) * 64 + (node & 1) * 32 + (k >> 3) * 8 + (k & 7);
    meta[didx] = make_int2(idx * ROWB, __float_as_int(w));
}

// ---- prep: xT[row][batch] f32; rows 0..127 = x^T, 128 = 0.0, 129 = 1.0 ----
__global__ __launch_bounds__(256) void prep_xt(const float* __restrict__ x,
                                               float* __restrict__ xT) {
    int g = blockIdx.x * 256 + threadIdx.x;      // 130*1024 = 133,120 exact
    int r = g >> 10, b = g & 1023;
    float v = (r < 128) ? x[(size_t)b * 128 + r] : ((r == 128) ? 0.0f : 1.0f);
    xT[(size_t)r * NBATCH + b] = v;
}

// ---- main: 1 wave / (net, 16-batch tile); f32 state in LDS; depth-3 meta pipeline ----
// lane = kq(2b: K quarter) | s(1b: node of pair) | p(3b: batch pair)
template <bool F32OUT>
__global__ __launch_bounds__(64) void unn_main(const float* __restrict__ xT,
                                               const int2* __restrict__ meta,
                                               void* __restrict__ outsv) {
    __shared__ float Hf[LDSZ / 4];
    char* Hl = (char*)Hf;
    const int lane = threadIdx.x;
    const int p    = lane & 7;
    const int s    = (lane >> 3) & 1;
    const int kq   = lane >> 4;
    int bid = (int)blockIdx.x;
    bid = (bid & 7) * 512 + (bid >> 3);          // XCD swizzle (4096 % 8 == 0, bijective)
    const int net = bid >> 6;
    const int b0  = (bid & 63) * TILE;

    // stage rows 0..129: 520 float4, linear lane->byte mapping (conflict-free)
    for (int i = lane; i < 520; i += 64) {
        int row = i >> 2, c = i & 3;
        float4 v = *(const float4*)(xT + (size_t)row * NBATCH + b0 + c * 4);
        *(float4*)(Hl + row * ROWB + c * 16) = v;
    }
    __syncthreads();

    const int2* mbase = meta + (size_t)net * 9216 + (s * 4 + kq) * 8;
    const char* Hp = Hl + p * 8;
    float*          o32p = (float*)outsv        + (size_t)net * NOUT * NBATCH + b0 + 2 * p;
    unsigned short* o16p = (unsigned short*)outsv + (size_t)net * NOUT * NBATCH + b0 + 2 * p;

    int4 A[4], B[4], C[4];

    auto PREF = [&](int4 (&M)[4], int t) {
        const int4* mp = (const int4*)(mbase + (size_t)t * 64);
        #pragma unroll
        for (int j = 0; j < 4; ++j) M[j] = mp[j];
    };

    auto BODY = [&](const int4 (&M)[4], int t) {
        float ax0 = 0.f, ay0 = 0.f, ax1 = 0.f, ay1 = 0.f;
        #pragma unroll
        for (int j = 0; j < 4; ++j) {
            int4 m = M[j];
            float2 v0 = *(const float2*)(Hp + m.x);
            float2 v1 = *(const float2*)(Hp + m.z);
            float w0 = __int_as_float(m.y), w1 = __int_as_float(m.w);
            if (j & 1) {
                ax1 = fmaf(w0, v0.x, ax1); ay1 = fmaf(w0, v0.y, ay1);
                ax1 = fmaf(w1, v1.x, ax1); ay1 = fmaf(w1, v1.y, ay1);
            } else {
                ax0 = fmaf(w0, v0.x, ax0); ay0 = fmaf(w0, v0.y, ay0);
                ax0 = fmaf(w1, v1.x, ax0); ay0 = fmaf(w1, v1.y, ay0);
            }
        }
        float ax = ax0 + ax1, ay = ay0 + ay1;
        ax = xor16_add(ax); ay = xor16_add(ay);   // sum over kq bit 0
        ax = xor32_add(ax); ay = xor32_add(ay);   // sum over kq bit 1
        float rx = fmaxf(ax, 0.01f * ax);
        float ry = fmaxf(ay, 0.01f * ay);
        int node = 2 * t + s;
        if (kq == 0) {
            if (node < NHID) {
                *(float2*)(Hl + (130 + node) * ROWB + p * 8) = make_float2(rx, ry);
            } else if (F32OUT) {
                *(float2*)(o32p + (size_t)(node - NHID) * NBATCH) = make_float2(rx, ry);
            } else {
                unsigned u = f2bf(rx) | (f2bf(ry) << 16);
                *(unsigned*)(o16p + (size_t)(node - NHID) * NBATCH) = u;
            }
        }
    };

    PREF(A, 0); PREF(B, 1); PREF(C, 2);
    for (int t = 0; t < NPAIR; t += 3) {          // 144 = 3*48, no tail
        BODY(A, t);     PREF(A, (t + 3 < NPAIR) ? t + 3 : NPAIR - 1);
        BODY(B, t + 1); PREF(B, (t + 4 < NPAIR) ? t + 4 : NPAIR - 1);
        BODY(C, t + 2); PREF(C, (t + 5 < NPAIR) ? t + 5 : NPAIR - 1);
    }
}

// ---- reduce: out[b][o] = sum_n softmax(nw)[n] * outs[n][o][b] ----
// grid: 512 blocks = (batch-tile 0..15) x (o 0..31), 64 threads
template <bool F32OUT>
__global__ __launch_bounds__(64) void unn_reduce(const float* __restrict__ nw,
                                                 const void* __restrict__ outsv,
                                                 float* __restrict__ out) {
    __shared__ float sw[NETS];
    int tt = threadIdx.x;
    int o  = blockIdx.x & 31;
    int bt = blockIdx.x >> 5;
    float v = nw[tt];
    float m = v;
    #pragma unroll
    for (int off = 32; off; off >>= 1) m = fmaxf(m, __shfl_xor(m, off, 64));
    float e = __expf(v - m);
    float ssum = e;
    #pragma unroll
    for (int off = 32; off; off >>= 1) ssum += __shfl_xor(ssum, off, 64);
    sw[tt] = e / ssum;
    __syncthreads();

    int bb = bt * 64 + tt;
    const float* o32 = (const float*)outsv;
    const unsigned short* o16 = (const unsigned short*)outsv;
    float acc = 0.f;
    #pragma unroll 8
    for (int n = 0; n < NETS; ++n) {
        size_t idx = ((size_t)n * NOUT + o) * NBATCH + bb;
        float val = F32OUT ? o32[idx] : bf2f(o16[idx]);
        acc = fmaf(sw[n], val, acc);
    }
    out[(size_t)bb * NOUT + o] = acc;
}

extern "C" void kernel_launch(void* const* d_in, const int* in_sizes, int n_in,
                              void* d_out, int out_size, void* d_ws, size_t ws_size,
                              hipStream_t stream) {
    const float* x    = (const float*)d_in[0];   // 1024*128
    const float* W    = (const float*)d_in[1];   // 386*288
    const float* nw   = (const float*)d_in[2];   // 64
    const int*   conn = (const int*)d_in[3];     // 64*288*32
    float* out = (float*)d_out;                  // 1024*32

    char* ws = (char*)d_ws;
    int2*  meta = (int2*)(ws);                   // 589,824 * 8 = 4,718,592
    float* xT   = (float*)(ws + 4718592);        // 130*1024*4  =   532,480
    void*  outs = (void*)(ws + 4718592 + 532480);// f32: 8,388,608 | bf16: 4,194,304

    const bool f32path = ws_size >= (size_t)4718592 + 532480 + 8388608;  // 13,639,680

    prep_meta<<<dim3(2304), dim3(256), 0, stream>>>(W, conn, meta);
    prep_xt  <<<dim3(520),  dim3(256), 0, stream>>>(x, xT);
    if (f32path) {
        unn_main<true> <<<dim3(NETS * (NBATCH/TILE)), dim3(64), 0, stream>>>(xT, meta, outs);
        unn_reduce<true> <<<dim3(512), dim3(64), 0, stream>>>(nw, outs, out);
    } else {
        unn_main<false> <<<dim3(NETS * (NBATCH/TILE)), dim3(64), 0, stream>>>(xT, meta, outs);
        unn_reduce<false> <<<dim3(512), dim3(64), 0, stream>>>(nw, outs, out);
    }
}